// Round 8
// baseline (413.587 us; speedup 1.0000x reference)
//
#include <hip/hip_runtime.h>

typedef float floatx4 __attribute__((ext_vector_type(4)));
typedef __bf16 bf16x8 __attribute__((ext_vector_type(8)));
using u16 = unsigned short;
using u32 = unsigned int;

#define GLOBAL_AS __attribute__((address_space(1)))
#define LDS_AS    __attribute__((address_space(3)))

// ---------------- conversion: x fp32 -> bf16 (RNE) ----------------
__global__ void cvt_x_kernel(const float* __restrict__ x, u16* __restrict__ xb, int n8) {
  int stride = gridDim.x * blockDim.x;
  for (int i = blockIdx.x * blockDim.x + threadIdx.x; i < n8; i += stride) {
    const float4* p = (const float4*)(x + (size_t)i * 8);
    float4 a = p[0], b = p[1];
    float v[8] = {a.x, a.y, a.z, a.w, b.x, b.y, b.z, b.w};
    u32 r[8];
#pragma unroll
    for (int j = 0; j < 8; ++j) {
      u32 u = __float_as_uint(v[j]);
      r[j] = (u + 0x7FFFu + ((u >> 16) & 1u)) >> 16;  // RNE
    }
    uint4 o;
    o.x = r[0] | (r[1] << 16);
    o.y = r[2] | (r[3] << 16);
    o.z = r[4] | (r[5] << 16);
    o.w = r[6] | (r[7] << 16);
    *(uint4*)(xb + (size_t)i * 8) = o;
  }
}

// ---------------- quantize: w fp32 -> ternary {-1,0,+1} as bf16 bits (row-major) ----------------
__global__ void quant_w_kernel(const float* __restrict__ w, u16* __restrict__ wb, int n8) {
  int stride = gridDim.x * blockDim.x;
  for (int i = blockIdx.x * blockDim.x + threadIdx.x; i < n8; i += stride) {
    const float4* p = (const float4*)(w + (size_t)i * 8);
    float4 a = p[0], b = p[1];
    float v[8] = {a.x, a.y, a.z, a.w, b.x, b.y, b.z, b.w};
    u32 r[8];
#pragma unroll
    for (int j = 0; j < 8; ++j) {
      r[j] = (v[j] > 0.05f) ? 0x3F80u : ((v[j] < -0.05f) ? 0xBF80u : 0u);
    }
    uint4 o;
    o.x = r[0] | (r[1] << 16);
    o.y = r[2] | (r[3] << 16);
    o.z = r[4] | (r[5] << 16);
    o.w = r[6] | (r[7] << 16);
    *(uint4*)(wb + (size_t)i * 8) = o;
  }
}

// ---------------- 256x128 BK=32 bf16 GEMM, ring-3 LDS, 2 blocks/CU (4 waves/SIMD) ----------------
// out[m][n] = sum_k A[m][k]*B[n][k] + bias[n]. 8 waves (4x2), per-wave 64x64
// (acc 16 frags = 64 regs -> unified RF ~120 -> 4 waves/SIMD via launch_bounds).
// LDS ring-3 x 24KB (A 16KB frag-ordered | B 8KB) = 72KB -> 2 resident blocks/CU:
// independent barrier domains drift -> one block's LDS reads hide under the
// other's MFMAs (the serialization that pinned rounds 2-7 at ~40% MfmaUtil).
// Per step s: stage slot (s+2)%3 (3 gload_lds, fragment-permuted source, linear
// dest, zero-conflict reads); 8 ds_reads; lgkm(2)->8 MFMA; lgkm(0)->8 MFMA;
// vmcnt(3) [drains stage(s+1), keeps s+2 in flight -- never 0 until tail]; barrier.
__global__ __launch_bounds__(512, 4) void gemm_bin_r3(
    const u16* __restrict__ A, const u16* __restrict__ B,
    const float* __restrict__ bias, float* __restrict__ C,
    int M, int N, int K) {
  __shared__ u16 lds[36864];  // 3 x 12288 u16 = 72 KiB

  const int tid = threadIdx.x;
  const int w = tid >> 6, l = tid & 63;
  const int wr = w >> 1, wc = w & 1;   // 4x2 wave grid, 64x64 each
  const int r = l & 15;

  const int nbn = N >> 7;
  int wg = blockIdx.x;
  const int nwg = gridDim.x;
  if ((nwg & 7) == 0) wg = (wg & 7) * (nwg >> 3) + (wg >> 3);  // XCD swizzle (bijective)
  const int bm = wg / nbn, bn = wg % nbn;

  const int S = K >> 5;  // K-steps of 32

  // fragment-permuted staging source: thread t -> frag fi=t>>6, lane ll=t&63
  //   row = fi*16 + (t&15), k-part = ((t>>4)&3)*8   (linear LDS dest = t*8)
  const int frow = ((tid >> 6) << 4) + (tid & 15);
  const int fk = ((tid >> 4) & 3) << 3;
  const u16* const srcA = A + (size_t)(bm * 256 + frow) * K + fk;          // gload 0: frags 0-7
  const u16* const srcA2 = srcA + (size_t)128 * K;                          // gload 1: frags 8-15
  const u16* const srcB = B + (size_t)(bn * 128 + frow) * K + fk;          // frags 0-7

  // wave read bases (u16 elems within slot): A frag (wr*4+m)*512, B 8192+(wc*4+n)*512
  const u16* const afp0 = lds + (wr * 4) * 512 + l * 8;
  const u16* const bfp0 = lds + 8192 + (wc * 4) * 512 + l * 8;

  floatx4 acc[4][4] = {};
  bf16x8 af[4], bf[4];

#define GLOAD(gptr, u16off)                                                    \
  __builtin_amdgcn_global_load_lds((const GLOBAL_AS void*)(gptr),              \
                                   (LDS_AS void*)(lds + (u16off)), 16, 0, 0)
#define STAGE(ss, slot_)                                                       \
  {                                                                            \
    const size_t ko_ = (size_t)(ss) << 5;                                      \
    GLOAD(srcA + ko_,  (slot_) * 12288 + tid * 8);                             \
    GLOAD(srcA2 + ko_, (slot_) * 12288 + 4096 + tid * 8);                      \
    GLOAD(srcB + ko_,  (slot_) * 12288 + 8192 + tid * 8);                      \
  }

  // prologue: stage steps 0,1 into slots 0,1
  STAGE(0, 0)
  STAGE(1, 1)
  asm volatile("s_waitcnt vmcnt(3)" ::: "memory");  // slot 0 landed
  __builtin_amdgcn_s_barrier();

  int slot = 0, slot2 = 2;  // slot = s%3, slot2 = (s+2)%3
  for (int s = 0; s < S; ++s) {
    if (s + 2 < S) STAGE(s + 2, slot2)

    const u16* afp = afp0 + slot * 12288;
    const u16* bfp = bfp0 + slot * 12288;
#pragma unroll
    for (int m = 0; m < 4; ++m) af[m] = *(const bf16x8*)(afp + m * 512);
    bf[0] = *(const bf16x8*)(bfp + 0 * 512);
    bf[1] = *(const bf16x8*)(bfp + 1 * 512);
    bf[2] = *(const bf16x8*)(bfp + 2 * 512);
    bf[3] = *(const bf16x8*)(bfp + 3 * 512);

    asm volatile("s_waitcnt lgkmcnt(2)" ::: "memory");  // af[0..3]+bf[0..1] landed
    __builtin_amdgcn_sched_barrier(0);
    __builtin_amdgcn_s_setprio(1);
#pragma unroll
    for (int m = 0; m < 4; ++m)
#pragma unroll
      for (int n = 0; n < 2; ++n)
        acc[m][n] = __builtin_amdgcn_mfma_f32_16x16x32_bf16(af[m], bf[n], acc[m][n], 0, 0, 0);
    __builtin_amdgcn_s_setprio(0);

    asm volatile("s_waitcnt lgkmcnt(0)" ::: "memory");  // bf[2..3] landed
    __builtin_amdgcn_sched_barrier(0);
    __builtin_amdgcn_s_setprio(1);
#pragma unroll
    for (int m = 0; m < 4; ++m)
#pragma unroll
      for (int n = 2; n < 4; ++n)
        acc[m][n] = __builtin_amdgcn_mfma_f32_16x16x32_bf16(af[m], bf[n], acc[m][n], 0, 0, 0);
    __builtin_amdgcn_s_setprio(0);

    if (s + 1 < S) {
      if (s + 2 < S) asm volatile("s_waitcnt vmcnt(3)" ::: "memory");  // drain stage(s+1)
      else           asm volatile("s_waitcnt vmcnt(0)" ::: "memory");
      __builtin_amdgcn_s_barrier();
    }
    slot = (slot == 2) ? 0 : slot + 1;
    slot2 = (slot2 == 2) ? 0 : slot2 + 1;
  }
#undef STAGE
#undef GLOAD

  // ---- epilogue: C/D layout col = l&15, row = (l>>4)*4 + q (m89/m91-verified) ----
  const int g = l >> 4;
  const int colb = bn * 128 + wc * 64;
  float bv[4];
#pragma unroll
  for (int n = 0; n < 4; ++n) bv[n] = bias[colb + n * 16 + r];
  const int rowb0 = bm * 256 + wr * 64;
#pragma unroll
  for (int m = 0; m < 4; ++m) {
    const int rowb = rowb0 + m * 16 + g * 4;
#pragma unroll
    for (int n = 0; n < 4; ++n) {
      const int col = colb + n * 16 + r;
      float* cp = C + (size_t)rowb * N + col;
#pragma unroll
      for (int q = 0; q < 4; ++q) cp[(size_t)q * N] = acc[m][n][q] + bv[n];
    }
  }
}

// ---------------- fallback: slow but correct ----------------
__global__ void gemm_naive_kernel(const float* __restrict__ x, const float* __restrict__ wgt,
                                  const float* __restrict__ bias, float* __restrict__ out,
                                  int M, int N, int K) {
  long long idx = (long long)blockIdx.x * blockDim.x + threadIdx.x;
  if (idx >= (long long)M * N) return;
  int o = (int)(idx % N);
  int m = (int)(idx / N);
  const float* xr = x + (size_t)m * K;
  const float* wr = wgt + (size_t)o * K;
  float s = 0.f;
  for (int i = 0; i < K; ++i) {
    float wv = wr[i];
    float t = (wv > 0.05f) ? 1.f : ((wv < -0.05f) ? -1.f : 0.f);
    s = fmaf(xr[i], t, s);
  }
  out[idx] = s + bias[o];
}

extern "C" void kernel_launch(void* const* d_in, const int* in_sizes, int n_in,
                              void* d_out, int out_size, void* d_ws, size_t ws_size,
                              hipStream_t stream) {
  const float* x    = (const float*)d_in[0];
  const float* wgt  = (const float*)d_in[1];
  const float* bias = (const float*)d_in[2];
  float* out = (float*)d_out;

  const int N = in_sizes[2];                 // out features
  const int K = in_sizes[1] / N;             // in features
  const int M = in_sizes[0] / K;             // batch rows

  const size_t need = ((size_t)M * K + (size_t)N * K) * sizeof(u16);
  if (ws_size >= need && (M % 256 == 0) && (N % 128 == 0) && (K % 32 == 0) && K >= 96) {
    u16* xb = (u16*)d_ws;
    u16* wb = xb + (size_t)M * K;
    const int nx8 = (M * K) / 8;
    const int nw8 = (N * K) / 8;
    cvt_x_kernel<<<2048, 256, 0, stream>>>(x, xb, nx8);
    quant_w_kernel<<<2048, 256, 0, stream>>>(wgt, wb, nw8);
    const int grid = (M / 256) * (N / 128);
    gemm_bin_r3<<<grid, 512, 0, stream>>>(xb, wb, bias, out, M, N, K);
  } else {
    const long long total = (long long)M * N;
    gemm_naive_kernel<<<(unsigned)((total + 255) / 256), 256, 0, stream>>>(x, wgt, bias, out, M, N, K);
  }
}

// Round 9
// 356.986 us; speedup vs baseline: 1.1586x; 1.1586x over previous
//
#include <hip/hip_runtime.h>

typedef float floatx4 __attribute__((ext_vector_type(4)));
typedef __bf16 bf16x8 __attribute__((ext_vector_type(8)));
using u16 = unsigned short;
using u32 = unsigned int;

#define GLOBAL_AS __attribute__((address_space(1)))
#define LDS_AS    __attribute__((address_space(3)))

// ---------------- x fp32 -> bf16 (RNE), written in GEMM-LDS-image order ----------------
// Aperm u16 index = panel*(256*K) + tile*16384 + g*4096 + tid*8, where
// g = (row&255)>>6, rr = row&63, tid = ((rr>>4)<<7)|(((k&63)>>5)<<6)|((((k&63)>>3)&3)<<4)|(rr&15).
// (Exact inverse of the round-5 staging equations -> LDS content bit-identical to R5.)
__global__ void cvt_x_perm(const float* __restrict__ x, u16* __restrict__ xb,
                           int K, int Kd8, int n8) {
  int stride = gridDim.x * blockDim.x;
  for (int i = blockIdx.x * blockDim.x + threadIdx.x; i < n8; i += stride) {
    const int row = i / Kd8;
    const int k = (i - row * Kd8) * 8;
    const float4* p = (const float4*)(x + (size_t)row * K + k);
    float4 a = p[0], b = p[1];
    float v[8] = {a.x, a.y, a.z, a.w, b.x, b.y, b.z, b.w};
    u32 r[8];
#pragma unroll
    for (int j = 0; j < 8; ++j) {
      u32 u = __float_as_uint(v[j]);
      r[j] = (u + 0x7FFFu + ((u >> 16) & 1u)) >> 16;  // RNE
    }
    uint4 o;
    o.x = r[0] | (r[1] << 16);
    o.y = r[2] | (r[3] << 16);
    o.z = r[4] | (r[5] << 16);
    o.w = r[6] | (r[7] << 16);
    const int pn = row >> 8, rl = row & 255;
    const int g = rl >> 6, rr = rl & 63;
    const int t = k >> 6, kl = k & 63;
    const int tid = ((rr >> 4) << 7) | (((kl >> 5) & 1) << 6) | (((kl >> 3) & 3) << 4) | (rr & 15);
    u16* dst = xb + (size_t)pn * ((size_t)K << 8) + (size_t)t * 16384 + g * 4096 + tid * 8;
    *(uint4*)dst = o;
  }
}

// ------- W -> ternary bf16, written in GEMM-LDS-image order (B quarters) -------
// Bperm u16 index = panel*(256*K) + tile*16384 + q*4096 + tid*8, where for n-local rl:
// q = ((rl>>7)&1) + (((rl>>5)&1)<<1); tid = (((rl>>6)&1)<<8)|(((rl>>4)&1)<<7)|
//       (((k&63)>>5)<<6)|((((k&63)>>3)&3)<<4)|(rl&15).  (Inverse of R5 B staging.)
__global__ void quant_w_perm(const float* __restrict__ w, u16* __restrict__ wb,
                             int K, int Kd8, int n8) {
  int stride = gridDim.x * blockDim.x;
  for (int i = blockIdx.x * blockDim.x + threadIdx.x; i < n8; i += stride) {
    const int n = i / Kd8;
    const int k = (i - n * Kd8) * 8;
    const float4* p = (const float4*)(w + (size_t)n * K + k);
    float4 a = p[0], b = p[1];
    float v[8] = {a.x, a.y, a.z, a.w, b.x, b.y, b.z, b.w};
    u32 r[8];
#pragma unroll
    for (int j = 0; j < 8; ++j) {
      r[j] = (v[j] > 0.05f) ? 0x3F80u : ((v[j] < -0.05f) ? 0xBF80u : 0u);
    }
    uint4 o;
    o.x = r[0] | (r[1] << 16);
    o.y = r[2] | (r[3] << 16);
    o.z = r[4] | (r[5] << 16);
    o.w = r[6] | (r[7] << 16);
    const int pn = n >> 8, rl = n & 255;
    const int q = ((rl >> 7) & 1) + (((rl >> 5) & 1) << 1);
    const int t = k >> 6, kl = k & 63;
    const int tid = (((rl >> 6) & 1) << 8) | (((rl >> 4) & 1) << 7) |
                    (((kl >> 5) & 1) << 6) | (((kl >> 3) & 3) << 4) | (rl & 15);
    u16* dst = wb + (size_t)pn * ((size_t)K << 8) + (size_t)t * 16384 + q * 4096 + tid * 8;
    *(uint4*)dst = o;
  }
}

// ---------------- 256x256 BK=64 4-phase bf16 GEMM (R5 schedule, linear staging) ----------------
// Identical to round-5 best (291us) except: A/B pre-permuted in global memory ->
// every global_load_lds source is LINEAR (panel + t*16384 + g*4096 + tid*8 u16):
// perfectly coalesced, full 64B-line utilization, contiguous 32KB tile streams.
// LDS content (and thus all reads/MFMA/epilogue) bit-identical to round 5.
__global__ __launch_bounds__(512, 2) void gemm_bin_lin(
    const u16* __restrict__ Ap, const u16* __restrict__ Bp,
    const float* __restrict__ bias, float* __restrict__ C,
    int M, int N, int K) {
  __shared__ u16 lds[65536];  // 128 KiB

  const int tid = threadIdx.x;
  const int w = tid >> 6, l = tid & 63;
  const int wr = w >> 2, wc = w & 3;
  const int r = l & 15;

  const int nbn = N >> 8;
  int wg = blockIdx.x;
  const int nwg = gridDim.x;
  if ((nwg & 7) == 0) wg = (wg & 7) * (nwg >> 3) + (wg >> 3);  // XCD swizzle (bijective)
  const int bm = wg / nbn, bn = wg % nbn;

  const int T = K >> 6;

  const u16* const Abase = Ap + (size_t)bm * ((size_t)K << 8) + tid * 8;
  const u16* const Bbase = Bp + (size_t)bn * ((size_t)K << 8) + tid * 8;

  const u16* const afp0 = lds + wr * 8192 + l * 8;
  const u16* const bfp0 = lds + 16384 + wc * 2048 + l * 8;

  floatx4 acc[8][4] = {};
  bf16x8 af[8], bflo[4], bfhi[4];

#define GLOAD(gptr, u16off)                                                    \
  __builtin_amdgcn_global_load_lds((const GLOBAL_AS void*)(gptr),              \
                                   (LDS_AS void*)(lds + (u16off)), 16, 0, 0)
#define BARRIER __builtin_amdgcn_s_barrier()
#define LGKM0  do { asm volatile("s_waitcnt lgkmcnt(0)" ::: "memory");         \
                    __builtin_amdgcn_sched_barrier(0); } while (0)

  // prologue: stage tile 0 into buf0 (order: A g0, A g2, B q0, B q1, B q2, B q3, A g1, A g3)
  GLOAD(Abase + 0 * 4096,      0 + tid * 8);
  GLOAD(Abase + 2 * 4096,   8192 + tid * 8);
  GLOAD(Bbase + 0 * 4096,  16384 + tid * 8);
  GLOAD(Bbase + 1 * 4096,  20480 + tid * 8);
  GLOAD(Bbase + 2 * 4096,  24576 + tid * 8);
  GLOAD(Bbase + 3 * 4096,  28672 + tid * 8);
  GLOAD(Abase + 1 * 4096,   4096 + tid * 8);
  GLOAD(Abase + 3 * 4096,  12288 + tid * 8);
  asm volatile("s_waitcnt vmcnt(4)" ::: "memory");  // A g0,g2 + B q0,q1 landed
  BARRIER;

  for (int t = 0; t < T; ++t) {
    const int bufc = (t & 1) << 15;
    const int bufn = bufc ^ 32768;
    const bool doSt = (t + 1 < T);
    const size_t tn = (size_t)(t + 1) * 16384;

    const u16* afp = afp0 + bufc;
    const u16* bfp = bfp0 + bufc;

    // ---- P1: af m0 (8) + bflo (4); stage A g0,g2; Q(m0,n01) ----
#pragma unroll
    for (int i = 0; i < 8; ++i) af[i] = *(const bf16x8*)(afp + i * 512);
#pragma unroll
    for (int i = 0; i < 4; ++i) bflo[i] = *(const bf16x8*)(bfp + i * 512);
    if (doSt) {
      GLOAD(Abase + tn + 0 * 4096, bufn + 0 + tid * 8);
      GLOAD(Abase + tn + 2 * 4096, bufn + 8192 + tid * 8);
    }
    asm volatile("s_waitcnt lgkmcnt(8)" ::: "memory");
    BARRIER;
    LGKM0;
    __builtin_amdgcn_s_setprio(1);
#pragma unroll
    for (int j = 0; j < 2; ++j)
#pragma unroll
      for (int mg = 0; mg < 4; ++mg)
#pragma unroll
        for (int ng = 0; ng < 2; ++ng)
          acc[mg][ng] = __builtin_amdgcn_mfma_f32_16x16x32_bf16(
              af[mg * 2 + j], bflo[ng * 2 + j], acc[mg][ng], 0, 0, 0);
    __builtin_amdgcn_s_setprio(0);
    if (doSt) asm volatile("s_waitcnt vmcnt(4)" ::: "memory");
    else      asm volatile("s_waitcnt vmcnt(2)" ::: "memory");
    BARRIER;

    // ---- P2: bfhi (4); stage B q0,q1; Q(m0,n23) ----
#pragma unroll
    for (int i = 0; i < 4; ++i) bfhi[i] = *(const bf16x8*)(bfp + 8192 + i * 512);
    if (doSt) {
      GLOAD(Bbase + tn + 0 * 4096, bufn + 16384 + tid * 8);
      GLOAD(Bbase + tn + 1 * 4096, bufn + 20480 + tid * 8);
    }
    BARRIER;
    LGKM0;
    __builtin_amdgcn_s_setprio(1);
#pragma unroll
    for (int j = 0; j < 2; ++j)
#pragma unroll
      for (int mg = 0; mg < 4; ++mg)
#pragma unroll
        for (int ng = 0; ng < 2; ++ng)
          acc[mg][2 + ng] = __builtin_amdgcn_mfma_f32_16x16x32_bf16(
              af[mg * 2 + j], bfhi[ng * 2 + j], acc[mg][2 + ng], 0, 0, 0);
    __builtin_amdgcn_s_setprio(0);
    if (doSt) asm volatile("s_waitcnt vmcnt(4)" ::: "memory");
    else      asm volatile("s_waitcnt vmcnt(0)" ::: "memory");
    BARRIER;

    // ---- P3: af m1 (8); stage B q2,q3; Q(m1,n01) ----
#pragma unroll
    for (int i = 0; i < 8; ++i) af[i] = *(const bf16x8*)(afp + 4096 + i * 512);
    if (doSt) {
      GLOAD(Bbase + tn + 2 * 4096, bufn + 24576 + tid * 8);
      GLOAD(Bbase + tn + 3 * 4096, bufn + 28672 + tid * 8);
    }
    asm volatile("s_waitcnt lgkmcnt(4)" ::: "memory");
    BARRIER;
    LGKM0;
    __builtin_amdgcn_s_setprio(1);
#pragma unroll
    for (int j = 0; j < 2; ++j)
#pragma unroll
      for (int mg = 0; mg < 4; ++mg)
#pragma unroll
        for (int ng = 0; ng < 2; ++ng)
          acc[4 + mg][ng] = __builtin_amdgcn_mfma_f32_16x16x32_bf16(
              af[mg * 2 + j], bflo[ng * 2 + j], acc[4 + mg][ng], 0, 0, 0);
    __builtin_amdgcn_s_setprio(0);
    if (doSt) asm volatile("s_waitcnt vmcnt(4)" ::: "memory");
    BARRIER;

    // ---- P4: stage A g1,g3; Q(m1,n23) ----
    if (doSt) {
      GLOAD(Abase + tn + 1 * 4096, bufn + 4096 + tid * 8);
      GLOAD(Abase + tn + 3 * 4096, bufn + 12288 + tid * 8);
    }
    BARRIER;
    __builtin_amdgcn_s_setprio(1);
#pragma unroll
    for (int j = 0; j < 2; ++j)
#pragma unroll
      for (int mg = 0; mg < 4; ++mg)
#pragma unroll
        for (int ng = 0; ng < 2; ++ng)
          acc[4 + mg][2 + ng] = __builtin_amdgcn_mfma_f32_16x16x32_bf16(
              af[mg * 2 + j], bfhi[ng * 2 + j], acc[4 + mg][2 + ng], 0, 0, 0);
    __builtin_amdgcn_s_setprio(0);
    if (doSt) asm volatile("s_waitcnt vmcnt(4)" ::: "memory");
    BARRIER;
  }
#undef GLOAD
#undef BARRIER
#undef LGKM0

  // ---- epilogue: C/D layout col = l&15, row = (l>>4)*4 + q (m89/m91-verified) ----
  const int g = l >> 4;
  const int colb = bn * 256 + wc * 64;
  float bv[4];
#pragma unroll
  for (int n = 0; n < 4; ++n) bv[n] = bias[colb + n * 16 + r];
  const int rowb0 = bm * 256 + wr * 128;
#pragma unroll
  for (int m = 0; m < 8; ++m) {
    const int rowb = rowb0 + m * 16 + g * 4;
#pragma unroll
    for (int n = 0; n < 4; ++n) {
      const int col = colb + n * 16 + r;
      float* cp = C + (size_t)rowb * N + col;
#pragma unroll
      for (int q = 0; q < 4; ++q) cp[(size_t)q * N] = acc[m][n][q] + bv[n];
    }
  }
}

// ---------------- fallback: slow but correct ----------------
__global__ void gemm_naive_kernel(const float* __restrict__ x, const float* __restrict__ wgt,
                                  const float* __restrict__ bias, float* __restrict__ out,
                                  int M, int N, int K) {
  long long idx = (long long)blockIdx.x * blockDim.x + threadIdx.x;
  if (idx >= (long long)M * N) return;
  int o = (int)(idx % N);
  int m = (int)(idx / N);
  const float* xr = x + (size_t)m * K;
  const float* wr = wgt + (size_t)o * K;
  float s = 0.f;
  for (int i = 0; i < K; ++i) {
    float wv = wr[i];
    float t = (wv > 0.05f) ? 1.f : ((wv < -0.05f) ? -1.f : 0.f);
    s = fmaf(xr[i], t, s);
  }
  out[idx] = s + bias[o];
}

extern "C" void kernel_launch(void* const* d_in, const int* in_sizes, int n_in,
                              void* d_out, int out_size, void* d_ws, size_t ws_size,
                              hipStream_t stream) {
  const float* x    = (const float*)d_in[0];
  const float* wgt  = (const float*)d_in[1];
  const float* bias = (const float*)d_in[2];
  float* out = (float*)d_out;

  const int N = in_sizes[2];                 // out features
  const int K = in_sizes[1] / N;             // in features
  const int M = in_sizes[0] / K;             // batch rows

  const size_t need = ((size_t)M * K + (size_t)N * K) * sizeof(u16);
  if (ws_size >= need && (M % 256 == 0) && (N % 256 == 0) && (K % 64 == 0) && K >= 128) {
    u16* xb = (u16*)d_ws;
    u16* wb = xb + (size_t)M * K;
    const int nx8 = (M * K) / 8;
    const int nw8 = (N * K) / 8;
    cvt_x_perm<<<2048, 256, 0, stream>>>(x, xb, K, K / 8, nx8);
    quant_w_perm<<<2048, 256, 0, stream>>>(wgt, wb, K, K / 8, nw8);
    const int grid = (M / 256) * (N / 256);
    gemm_bin_lin<<<grid, 512, 0, stream>>>(xb, wb, bias, out, M, N, K);
  } else {
    const long long total = (long long)M * N;
    gemm_naive_kernel<<<(unsigned)((total + 255) / 256), 256, 0, stream>>>(x, wgt, bias, out, M, N, K);
  }
}

// Round 10
// 297.020 us; speedup vs baseline: 1.3925x; 1.2019x over previous
//
#include <hip/hip_runtime.h>

typedef float floatx16 __attribute__((ext_vector_type(16)));
typedef __bf16 bf16x8 __attribute__((ext_vector_type(8)));
using u16 = unsigned short;
using u32 = unsigned int;

#define GLOBAL_AS __attribute__((address_space(1)))
#define LDS_AS    __attribute__((address_space(3)))

__device__ __forceinline__ u32 rne_bf16(float f) {
  u32 u = __float_as_uint(f);
  return (u + 0x7FFFu + ((u >> 16) & 1u)) >> 16;  // RNE
}

// ---------------- A: fp32 -> bf16, tile-permuted for 32x32x16 frags ----------------
// Tile (pn,tt) = rows pn*256.., k tt*64.. ; within-tile u16 idx =
//   gi*2048 + ks*512 + lane*8 + (klo&7)   [gi=row>>5 local, ks=klo>>4,
//   lane=(row&31)+32*((klo>>3)&1)] -- exact inverse of the GEMM frag read.
// Block: coalesced fp32 reads -> LDS permute -> LINEAR 32KB write.
__global__ __launch_bounds__(256) void cvt_x_perm(const float* __restrict__ x,
                                                  u16* __restrict__ xb, int K) {
  __shared__ u16 sm[16384];
  const int tid = threadIdx.x;
  const int Kt = K >> 6;
  const int pn = blockIdx.x / Kt, tt = blockIdx.x % Kt;
  const float* src = x + (size_t)pn * 256 * K + tt * 64;
#pragma unroll
  for (int j = 0; j < 16; ++j) {
    const int fc = j * 256 + tid;             // float4 index in tile
    const int row = fc >> 4, kl4 = fc & 15;   // row 0..255, kl4 = k/4
    const float4 v = *(const float4*)(src + (size_t)row * K + kl4 * 4);
    uint2 o;
    o.x = rne_bf16(v.x) | (rne_bf16(v.y) << 16);
    o.y = rne_bf16(v.z) | (rne_bf16(v.w) << 16);
    const int gi = row >> 5, rowin = row & 31;
    const int ks = kl4 >> 2;
    const int lane = rowin + 32 * ((kl4 >> 1) & 1);
    const int e4 = (kl4 & 1) * 4;
    *(uint2*)(sm + gi * 2048 + ks * 512 + lane * 8 + e4) = o;
  }
  __syncthreads();
  u16* dst = xb + (size_t)pn * 256 * K + (size_t)tt * 16384;
#pragma unroll
  for (int j = 0; j < 8; ++j) {
    const int o = (j * 256 + tid) * 8;
    *(uint4*)(dst + o) = *(const uint4*)(sm + o);
  }
}

// ---------------- B: fp32 -> ternary bf16, same tile-permuted layout ----------------
__global__ __launch_bounds__(256) void quant_w_perm(const float* __restrict__ w,
                                                    u16* __restrict__ wb, int K) {
  __shared__ u16 sm[16384];
  const int tid = threadIdx.x;
  const int Kt = K >> 6;
  const int pn = blockIdx.x / Kt, tt = blockIdx.x % Kt;
  const float* src = w + (size_t)pn * 256 * K + tt * 64;
#pragma unroll
  for (int j = 0; j < 16; ++j) {
    const int fc = j * 256 + tid;
    const int row = fc >> 4, kl4 = fc & 15;
    const float4 v = *(const float4*)(src + (size_t)row * K + kl4 * 4);
    float vv[4] = {v.x, v.y, v.z, v.w};
    u32 r[4];
#pragma unroll
    for (int e = 0; e < 4; ++e)
      r[e] = (vv[e] > 0.05f) ? 0x3F80u : ((vv[e] < -0.05f) ? 0xBF80u : 0u);
    uint2 o;
    o.x = r[0] | (r[1] << 16);
    o.y = r[2] | (r[3] << 16);
    const int gi = row >> 5, rowin = row & 31;
    const int ks = kl4 >> 2;
    const int lane = rowin + 32 * ((kl4 >> 1) & 1);
    const int e4 = (kl4 & 1) * 4;
    *(uint2*)(sm + gi * 2048 + ks * 512 + lane * 8 + e4) = o;
  }
  __syncthreads();
  u16* dst = wb + (size_t)pn * 256 * K + (size_t)tt * 16384;
#pragma unroll
  for (int j = 0; j < 8; ++j) {
    const int o = (j * 256 + tid) * 8;
    *(uint4*)(dst + o) = *(const uint4*)(sm + o);
  }
}

// ---------------- 256x256 BK=64 4-phase GEMM, mfma 32x32x16, linear staging ----------------
// R9 schedule; fragments now 32x32x16 (A/B: row|col=l&31, k=(l>>5)*8+j;
// C/D: col=l&31, row=(reg&3)+8*(reg>>2)+4*(l>>5), m74/m101-verified).
// 8 waves (2x4), per-wave 128x64 = acc[4][2] x floatx16. Per tile (K=64):
// A frag (gi=wr*4+m, ks): u16 gi*2048+ks*512+l*8 ; B frag (ni=wc*2+n, ks):
// 16384+ni*2048+ks*512+l*8. A chunk c = gi{2c,2c+1}; B chunk q = ni{2q,2q+1}
// -> wave wc's B lives wholly in chunk wc.
// Staging: P1 A-chunks{0,2}, P2 B{0,1}, P3 B{2,3}, P4 A{1,3}. vmcnt FIFO:
// end-P1/2/3 vmcnt(4); end-P4 vmcnt(2) (must drain P2+P3's B for next P1's
// bflo which spans ALL B chunks); prologue vmcnt(2).
__global__ __launch_bounds__(512, 2) void gemm_bin_3232(
    const u16* __restrict__ Ap, const u16* __restrict__ Bp,
    const float* __restrict__ bias, float* __restrict__ C,
    int M, int N, int K) {
  __shared__ u16 lds[65536];  // 128 KiB: 2 buf x (A 16384 | B 16384)

  const int tid = threadIdx.x;
  const int w = tid >> 6, l = tid & 63;
  const int wr = w >> 2, wc = w & 3;

  const int nbn = N >> 8;
  int wg = blockIdx.x;
  const int nwg = gridDim.x;
  if ((nwg & 7) == 0) wg = (wg & 7) * (nwg >> 3) + (wg >> 3);  // XCD swizzle (bijective)
  const int bm = wg / nbn, bn = wg % nbn;

  const int T = K >> 6;

  const u16* const Abase = Ap + (size_t)bm * ((size_t)K << 8) + tid * 8;
  const u16* const Bbase = Bp + (size_t)bn * ((size_t)K << 8) + tid * 8;

  const u16* const afp0 = lds + wr * 8192 + l * 8;            // + m*2048 + ks*512 (+4096 for m2,3)
  const u16* const bfp0 = lds + 16384 + wc * 4096 + l * 8;    // + n*2048 + ks*512

  floatx16 acc[4][2] = {};
  bf16x8 af[8], bflo[4], bfhi[4];

#define GLOAD(gptr, u16off)                                                    \
  __builtin_amdgcn_global_load_lds((const GLOBAL_AS void*)(gptr),              \
                                   (LDS_AS void*)(lds + (u16off)), 16, 0, 0)
#define BARRIER __builtin_amdgcn_s_barrier()
#define LGKM0  do { asm volatile("s_waitcnt lgkmcnt(0)" ::: "memory");         \
                    __builtin_amdgcn_sched_barrier(0); } while (0)

  // prologue: tile 0 -> buf0 (A c0, A c2, B q0, B q1, B q2, B q3, A c1, A c3)
  GLOAD(Abase + 0 * 4096,      0 + tid * 8);
  GLOAD(Abase + 2 * 4096,   8192 + tid * 8);
  GLOAD(Bbase + 0 * 4096,  16384 + tid * 8);
  GLOAD(Bbase + 1 * 4096,  20480 + tid * 8);
  GLOAD(Bbase + 2 * 4096,  24576 + tid * 8);
  GLOAD(Bbase + 3 * 4096,  28672 + tid * 8);
  GLOAD(Abase + 1 * 4096,   4096 + tid * 8);
  GLOAD(Abase + 3 * 4096,  12288 + tid * 8);
  asm volatile("s_waitcnt vmcnt(2)" ::: "memory");  // all but A c1,c3 landed
  BARRIER;

  for (int t = 0; t < T; ++t) {
    const int bufc = (t & 1) << 15;
    const int bufn = bufc ^ 32768;
    const bool doSt = (t + 1 < T);
    const size_t tn = (size_t)(t + 1) * 16384;

    const u16* afp = afp0 + bufc;
    const u16* bfp = bfp0 + bufc;

    // ---- P1: af m0,m1 (8) + bflo (4); stage A c0,c2; MFMA (m0,m1)x(n0) ----
#pragma unroll
    for (int m = 0; m < 2; ++m)
#pragma unroll
      for (int ks = 0; ks < 4; ++ks)
        af[m * 4 + ks] = *(const bf16x8*)(afp + m * 2048 + ks * 512);
#pragma unroll
    for (int ks = 0; ks < 4; ++ks) bflo[ks] = *(const bf16x8*)(bfp + ks * 512);
    if (doSt) {
      GLOAD(Abase + tn + 0 * 4096, bufn + 0 + tid * 8);
      GLOAD(Abase + tn + 2 * 4096, bufn + 8192 + tid * 8);
    }
    asm volatile("s_waitcnt lgkmcnt(8)" ::: "memory");
    BARRIER;
    LGKM0;
    __builtin_amdgcn_s_setprio(1);
#pragma unroll
    for (int ks = 0; ks < 4; ++ks)
#pragma unroll
      for (int m = 0; m < 2; ++m)
        acc[m][0] = __builtin_amdgcn_mfma_f32_32x32x16_bf16(
            af[m * 4 + ks], bflo[ks], acc[m][0], 0, 0, 0);
    __builtin_amdgcn_s_setprio(0);
    if (doSt) asm volatile("s_waitcnt vmcnt(4)" ::: "memory");
    else      asm volatile("s_waitcnt vmcnt(2)" ::: "memory");
    BARRIER;

    // ---- P2: bfhi (4); stage B q0,q1; MFMA (m0,m1)x(n1) ----
#pragma unroll
    for (int ks = 0; ks < 4; ++ks) bfhi[ks] = *(const bf16x8*)(bfp + 2048 + ks * 512);
    if (doSt) {
      GLOAD(Bbase + tn + 0 * 4096, bufn + 16384 + tid * 8);
      GLOAD(Bbase + tn + 1 * 4096, bufn + 20480 + tid * 8);
    }
    BARRIER;
    LGKM0;
    __builtin_amdgcn_s_setprio(1);
#pragma unroll
    for (int ks = 0; ks < 4; ++ks)
#pragma unroll
      for (int m = 0; m < 2; ++m)
        acc[m][1] = __builtin_amdgcn_mfma_f32_32x32x16_bf16(
            af[m * 4 + ks], bfhi[ks], acc[m][1], 0, 0, 0);
    __builtin_amdgcn_s_setprio(0);
    if (doSt) asm volatile("s_waitcnt vmcnt(4)" ::: "memory");
    else      asm volatile("s_waitcnt vmcnt(0)" ::: "memory");
    BARRIER;

    // ---- P3: af m2,m3 (8); stage B q2,q3; MFMA (m2,m3)x(n0) ----
#pragma unroll
    for (int m = 0; m < 2; ++m)
#pragma unroll
      for (int ks = 0; ks < 4; ++ks)
        af[m * 4 + ks] = *(const bf16x8*)(afp + 4096 + m * 2048 + ks * 512);
    if (doSt) {
      GLOAD(Bbase + tn + 2 * 4096, bufn + 24576 + tid * 8);
      GLOAD(Bbase + tn + 3 * 4096, bufn + 28672 + tid * 8);
    }
    asm volatile("s_waitcnt lgkmcnt(4)" ::: "memory");
    BARRIER;
    LGKM0;
    __builtin_amdgcn_s_setprio(1);
#pragma unroll
    for (int ks = 0; ks < 4; ++ks)
#pragma unroll
      for (int m = 0; m < 2; ++m)
        acc[2 + m][0] = __builtin_amdgcn_mfma_f32_32x32x16_bf16(
            af[m * 4 + ks], bflo[ks], acc[2 + m][0], 0, 0, 0);
    __builtin_amdgcn_s_setprio(0);
    if (doSt) asm volatile("s_waitcnt vmcnt(4)" ::: "memory");
    BARRIER;

    // ---- P4: stage A c1,c3; MFMA (m2,m3)x(n1) ----
    if (doSt) {
      GLOAD(Abase + tn + 1 * 4096, bufn + 4096 + tid * 8);
      GLOAD(Abase + tn + 3 * 4096, bufn + 12288 + tid * 8);
    }
    BARRIER;
    __builtin_amdgcn_s_setprio(1);
#pragma unroll
    for (int ks = 0; ks < 4; ++ks)
#pragma unroll
      for (int m = 0; m < 2; ++m)
        acc[2 + m][1] = __builtin_amdgcn_mfma_f32_32x32x16_bf16(
            af[m * 4 + ks], bfhi[ks], acc[2 + m][1], 0, 0, 0);
    __builtin_amdgcn_s_setprio(0);
    if (doSt) asm volatile("s_waitcnt vmcnt(2)" ::: "memory");
    BARRIER;
  }
#undef GLOAD
#undef BARRIER
#undef LGKM0

  // ---- epilogue: C/D col=l&31, row=(q&3)+8*(q>>2)+4*(l>>5) ----
  const int colq = l & 31;
  const int hi4 = (l >> 5) * 4;
#pragma unroll
  for (int m = 0; m < 4; ++m) {
    const int rowb = bm * 256 + wr * 128 + m * 32 + hi4;
#pragma unroll
    for (int n = 0; n < 2; ++n) {
      const int col = bn * 256 + wc * 64 + n * 32 + colq;
      const float bv = bias[col];
      float* cp = C + (size_t)rowb * N + col;
#pragma unroll
      for (int q = 0; q < 16; ++q) {
        const int dr = (q & 3) + 8 * (q >> 2);
        cp[(size_t)dr * N] = acc[m][n][q] + bv;
      }
    }
  }
}

// ---------------- fallback: slow but correct ----------------
__global__ void gemm_naive_kernel(const float* __restrict__ x, const float* __restrict__ wgt,
                                  const float* __restrict__ bias, float* __restrict__ out,
                                  int M, int N, int K) {
  long long idx = (long long)blockIdx.x * blockDim.x + threadIdx.x;
  if (idx >= (long long)M * N) return;
  int o = (int)(idx % N);
  int m = (int)(idx / N);
  const float* xr = x + (size_t)m * K;
  const float* wr = wgt + (size_t)o * K;
  float s = 0.f;
  for (int i = 0; i < K; ++i) {
    float wv = wr[i];
    float t = (wv > 0.05f) ? 1.f : ((wv < -0.05f) ? -1.f : 0.f);
    s = fmaf(xr[i], t, s);
  }
  out[idx] = s + bias[o];
}

extern "C" void kernel_launch(void* const* d_in, const int* in_sizes, int n_in,
                              void* d_out, int out_size, void* d_ws, size_t ws_size,
                              hipStream_t stream) {
  const float* x    = (const float*)d_in[0];
  const float* wgt  = (const float*)d_in[1];
  const float* bias = (const float*)d_in[2];
  float* out = (float*)d_out;

  const int N = in_sizes[2];                 // out features
  const int K = in_sizes[1] / N;             // in features
  const int M = in_sizes[0] / K;             // batch rows

  const size_t need = ((size_t)M * K + (size_t)N * K) * sizeof(u16);
  if (ws_size >= need && (M % 256 == 0) && (N % 256 == 0) && (K % 64 == 0) && K >= 128) {
    u16* xb = (u16*)d_ws;
    u16* wb = xb + (size_t)M * K;
    const int Kt = K / 64;
    cvt_x_perm<<<(M / 256) * Kt, 256, 0, stream>>>(x, xb, K);
    quant_w_perm<<<(N / 256) * Kt, 256, 0, stream>>>(wgt, wb, K);
    const int grid = (M / 256) * (N / 256);
    gemm_bin_3232<<<grid, 512, 0, stream>>>(xb, wb, bias, out, M, N, K);
  } else {
    const long long total = (long long)M * N;
    gemm_naive_kernel<<<(unsigned)((total + 255) / 256), 256, 0, stream>>>(x, wgt, bias, out, M, N, K);
  }
}

// Round 11
// 286.745 us; speedup vs baseline: 1.4424x; 1.0358x over previous
//
#include <hip/hip_runtime.h>

typedef float floatx16 __attribute__((ext_vector_type(16)));
typedef __bf16 bf16x8 __attribute__((ext_vector_type(8)));
using u16 = unsigned short;
using u32 = unsigned int;

#define GLOBAL_AS __attribute__((address_space(1)))
#define LDS_AS    __attribute__((address_space(3)))

__device__ __forceinline__ u32 rne_bf16(float f) {
  u32 u = __float_as_uint(f);
  return (u + 0x7FFFu + ((u >> 16) & 1u)) >> 16;  // RNE
}

// ---------------- A: fp32 -> bf16, tile-permuted for 32x32x16 frags ----------------
// (unchanged from R10: coalesced reads -> LDS permute -> linear 32KB writes)
__global__ __launch_bounds__(256) void cvt_x_perm(const float* __restrict__ x,
                                                  u16* __restrict__ xb, int K) {
  __shared__ u16 sm[16384];
  const int tid = threadIdx.x;
  const int Kt = K >> 6;
  const int pn = blockIdx.x / Kt, tt = blockIdx.x % Kt;
  const float* src = x + (size_t)pn * 256 * K + tt * 64;
#pragma unroll
  for (int j = 0; j < 16; ++j) {
    const int fc = j * 256 + tid;
    const int row = fc >> 4, kl4 = fc & 15;
    const float4 v = *(const float4*)(src + (size_t)row * K + kl4 * 4);
    uint2 o;
    o.x = rne_bf16(v.x) | (rne_bf16(v.y) << 16);
    o.y = rne_bf16(v.z) | (rne_bf16(v.w) << 16);
    const int gi = row >> 5, rowin = row & 31;
    const int ks = kl4 >> 2;
    const int lane = rowin + 32 * ((kl4 >> 1) & 1);
    const int e4 = (kl4 & 1) * 4;
    *(uint2*)(sm + gi * 2048 + ks * 512 + lane * 8 + e4) = o;
  }
  __syncthreads();
  u16* dst = xb + (size_t)pn * 256 * K + (size_t)tt * 16384;
#pragma unroll
  for (int j = 0; j < 8; ++j) {
    const int o = (j * 256 + tid) * 8;
    *(uint4*)(dst + o) = *(const uint4*)(sm + o);
  }
}

// ---------------- B: fp32 -> ternary bf16, same tile-permuted layout ----------------
__global__ __launch_bounds__(256) void quant_w_perm(const float* __restrict__ w,
                                                    u16* __restrict__ wb, int K) {
  __shared__ u16 sm[16384];
  const int tid = threadIdx.x;
  const int Kt = K >> 6;
  const int pn = blockIdx.x / Kt, tt = blockIdx.x % Kt;
  const float* src = w + (size_t)pn * 256 * K + tt * 64;
#pragma unroll
  for (int j = 0; j < 16; ++j) {
    const int fc = j * 256 + tid;
    const int row = fc >> 4, kl4 = fc & 15;
    const float4 v = *(const float4*)(src + (size_t)row * K + kl4 * 4);
    float vv[4] = {v.x, v.y, v.z, v.w};
    u32 r[4];
#pragma unroll
    for (int e = 0; e < 4; ++e)
      r[e] = (vv[e] > 0.05f) ? 0x3F80u : ((vv[e] < -0.05f) ? 0xBF80u : 0u);
    uint2 o;
    o.x = r[0] | (r[1] << 16);
    o.y = r[2] | (r[3] << 16);
    const int gi = row >> 5, rowin = row & 31;
    const int ks = kl4 >> 2;
    const int lane = rowin + 32 * ((kl4 >> 1) & 1);
    const int e4 = (kl4 & 1) * 4;
    *(uint2*)(sm + gi * 2048 + ks * 512 + lane * 8 + e4) = o;
  }
  __syncthreads();
  u16* dst = wb + (size_t)pn * 256 * K + (size_t)tt * 16384;
#pragma unroll
  for (int j = 0; j < 8; ++j) {
    const int o = (j * 256 + tid) * 8;
    *(uint4*)(dst + o) = *(const uint4*)(sm + o);
  }
}

// ---------------- 256x256 BK=64 GEMM, mfma 32x32x16, m201 vmcnt discipline ----------------
// R10 layout/reads/MFMA/epilogue. New stage calendar (2 gloads/phase, chunk-death-safe):
//   P1(t): A c1,c3 of (t+1) -> buf(t+1)   [died at P3(t-1)]
//   P2(t): A c0,c2 of (t+2) -> buf(t)     [died at P1(t)]
//   P3(t): B c0,c1 of (t+2) -> buf(t)     [died at P2(t)]
//   P4(t): B c2,c3 of (t+2) -> buf(t)     [died at P2(t)]
// Single counted wait per tile: end-P4 vmcnt(6) -- newest 6 = tile(t+2)'s loads,
// so ALL of tile t+1 has landed (RAW); each overwrite issues after the barrier
// closing its last reader phase (WAR). Prologue: tile0 (8) + tile1 A02/B01/B23 (6),
// vmcnt(6). Tail: t+2>=T -> no stages, end-P4 vmcnt(0).
__global__ __launch_bounds__(512, 2) void gemm_bin_m201d(
    const u16* __restrict__ Ap, const u16* __restrict__ Bp,
    const float* __restrict__ bias, float* __restrict__ C,
    int M, int N, int K) {
  __shared__ u16 lds[65536];  // 2 buf x (A 16384 | B 16384) u16

  const int tid = threadIdx.x;
  const int w = tid >> 6, l = tid & 63;
  const int wr = w >> 2, wc = w & 3;

  const int nbn = N >> 8;
  int wg = blockIdx.x;
  const int nwg = gridDim.x;
  if ((nwg & 7) == 0) wg = (wg & 7) * (nwg >> 3) + (wg >> 3);  // XCD swizzle (bijective)
  const int bm = wg / nbn, bn = wg % nbn;

  const int T = K >> 6;

  const u16* const Abase = Ap + (size_t)bm * ((size_t)K << 8) + tid * 8;
  const u16* const Bbase = Bp + (size_t)bn * ((size_t)K << 8) + tid * 8;

  const u16* const afp0 = lds + wr * 8192 + l * 8;
  const u16* const bfp0 = lds + 16384 + wc * 4096 + l * 8;

  floatx16 acc[4][2] = {};
  bf16x8 af[8], bflo[4], bfhi[4];

#define GLOAD(gptr, u16off)                                                    \
  __builtin_amdgcn_global_load_lds((const GLOBAL_AS void*)(gptr),              \
                                   (LDS_AS void*)(lds + (u16off)), 16, 0, 0)
#define BARRIER __builtin_amdgcn_s_barrier()
#define LGKM0  do { asm volatile("s_waitcnt lgkmcnt(0)" ::: "memory");         \
                    __builtin_amdgcn_sched_barrier(0); } while (0)

  // prologue: tile0 (A c0,c2 | B q0..q3 | A c1,c3) then tile1 (A c0,c2 | B q0..q3)
  GLOAD(Abase + 0 * 4096,      0 + tid * 8);
  GLOAD(Abase + 2 * 4096,   8192 + tid * 8);
  GLOAD(Bbase + 0 * 4096,  16384 + tid * 8);
  GLOAD(Bbase + 1 * 4096,  20480 + tid * 8);
  GLOAD(Bbase + 2 * 4096,  24576 + tid * 8);
  GLOAD(Bbase + 3 * 4096,  28672 + tid * 8);
  GLOAD(Abase + 1 * 4096,   4096 + tid * 8);
  GLOAD(Abase + 3 * 4096,  12288 + tid * 8);
  if (T > 1) {
    GLOAD(Abase + 16384 + 0 * 4096, 32768 + 0 + tid * 8);
    GLOAD(Abase + 16384 + 2 * 4096, 32768 + 8192 + tid * 8);
    GLOAD(Bbase + 16384 + 0 * 4096, 32768 + 16384 + tid * 8);
    GLOAD(Bbase + 16384 + 1 * 4096, 32768 + 20480 + tid * 8);
    GLOAD(Bbase + 16384 + 2 * 4096, 32768 + 24576 + tid * 8);
    GLOAD(Bbase + 16384 + 3 * 4096, 32768 + 28672 + tid * 8);
    asm volatile("s_waitcnt vmcnt(6)" ::: "memory");  // tile0 fully landed
  } else {
    asm volatile("s_waitcnt vmcnt(0)" ::: "memory");
  }
  BARRIER;

  for (int t = 0; t < T; ++t) {
    const int bufc = (t & 1) << 15;
    const int bufo = bufc ^ 32768;
    const bool st1 = (t + 1 < T);
    const bool st2 = (t + 2 < T);
    const size_t tn1 = (size_t)(t + 1) * 16384;
    const size_t tn2 = (size_t)(t + 2) * 16384;

    const u16* afp = afp0 + bufc;
    const u16* bfp = bfp0 + bufc;

    // ---- P1: af m0,m1 (8) + bflo (4); stage A c1,c3 (t+1)->bufo; MFMA (m0,m1)x(n0) ----
#pragma unroll
    for (int m = 0; m < 2; ++m)
#pragma unroll
      for (int ks = 0; ks < 4; ++ks)
        af[m * 4 + ks] = *(const bf16x8*)(afp + m * 2048 + ks * 512);
#pragma unroll
    for (int ks = 0; ks < 4; ++ks) bflo[ks] = *(const bf16x8*)(bfp + ks * 512);
    if (st1) {
      GLOAD(Abase + tn1 + 1 * 4096, bufo + 4096 + tid * 8);
      GLOAD(Abase + tn1 + 3 * 4096, bufo + 12288 + tid * 8);
    }
    asm volatile("s_waitcnt lgkmcnt(8)" ::: "memory");
    BARRIER;
    LGKM0;
    __builtin_amdgcn_s_setprio(1);
#pragma unroll
    for (int ks = 0; ks < 4; ++ks)
#pragma unroll
      for (int m = 0; m < 2; ++m)
        acc[m][0] = __builtin_amdgcn_mfma_f32_32x32x16_bf16(
            af[m * 4 + ks], bflo[ks], acc[m][0], 0, 0, 0);
    __builtin_amdgcn_s_setprio(0);
    BARRIER;

    // ---- P2: bfhi (4); stage A c0,c2 (t+2)->bufc; MFMA (m0,m1)x(n1) ----
#pragma unroll
    for (int ks = 0; ks < 4; ++ks) bfhi[ks] = *(const bf16x8*)(bfp + 2048 + ks * 512);
    if (st2) {
      GLOAD(Abase + tn2 + 0 * 4096, bufc + 0 + tid * 8);
      GLOAD(Abase + tn2 + 2 * 4096, bufc + 8192 + tid * 8);
    }
    BARRIER;
    LGKM0;
    __builtin_amdgcn_s_setprio(1);
#pragma unroll
    for (int ks = 0; ks < 4; ++ks)
#pragma unroll
      for (int m = 0; m < 2; ++m)
        acc[m][1] = __builtin_amdgcn_mfma_f32_32x32x16_bf16(
            af[m * 4 + ks], bfhi[ks], acc[m][1], 0, 0, 0);
    __builtin_amdgcn_s_setprio(0);
    BARRIER;

    // ---- P3: af m2,m3 (8); stage B c0,c1 (t+2)->bufc; MFMA (m2,m3)x(n0) ----
#pragma unroll
    for (int m = 0; m < 2; ++m)
#pragma unroll
      for (int ks = 0; ks < 4; ++ks)
        af[m * 4 + ks] = *(const bf16x8*)(afp + 4096 + m * 2048 + ks * 512);
    if (st2) {
      GLOAD(Bbase + tn2 + 0 * 4096, bufc + 16384 + tid * 8);
      GLOAD(Bbase + tn2 + 1 * 4096, bufc + 20480 + tid * 8);
    }
    asm volatile("s_waitcnt lgkmcnt(4)" ::: "memory");
    BARRIER;
    LGKM0;
    __builtin_amdgcn_s_setprio(1);
#pragma unroll
    for (int ks = 0; ks < 4; ++ks)
#pragma unroll
      for (int m = 0; m < 2; ++m)
        acc[2 + m][0] = __builtin_amdgcn_mfma_f32_32x32x16_bf16(
            af[m * 4 + ks], bflo[ks], acc[2 + m][0], 0, 0, 0);
    __builtin_amdgcn_s_setprio(0);
    BARRIER;

    // ---- P4: stage B c2,c3 (t+2)->bufc; MFMA (m2,m3)x(n1); vmcnt(6); barrier ----
    if (st2) {
      GLOAD(Bbase + tn2 + 2 * 4096, bufc + 24576 + tid * 8);
      GLOAD(Bbase + tn2 + 3 * 4096, bufc + 28672 + tid * 8);
    }
    BARRIER;
    __builtin_amdgcn_s_setprio(1);
#pragma unroll
    for (int ks = 0; ks < 4; ++ks)
#pragma unroll
      for (int m = 0; m < 2; ++m)
        acc[2 + m][1] = __builtin_amdgcn_mfma_f32_32x32x16_bf16(
            af[m * 4 + ks], bfhi[ks], acc[2 + m][1], 0, 0, 0);
    __builtin_amdgcn_s_setprio(0);
    if (st2) asm volatile("s_waitcnt vmcnt(6)" ::: "memory");
    else     asm volatile("s_waitcnt vmcnt(0)" ::: "memory");
    BARRIER;
  }
#undef GLOAD
#undef BARRIER
#undef LGKM0

  // ---- epilogue: C/D col=l&31, row=(q&3)+8*(q>>2)+4*(l>>5) (m74/m101-verified) ----
  const int colq = l & 31;
  const int hi4 = (l >> 5) * 4;
#pragma unroll
  for (int m = 0; m < 4; ++m) {
    const int rowb = bm * 256 + wr * 128 + m * 32 + hi4;
#pragma unroll
    for (int n = 0; n < 2; ++n) {
      const int col = bn * 256 + wc * 64 + n * 32 + colq;
      const float bv = bias[col];
      float* cp = C + (size_t)rowb * N + col;
#pragma unroll
      for (int q = 0; q < 16; ++q) {
        const int dr = (q & 3) + 8 * (q >> 2);
        cp[(size_t)dr * N] = acc[m][n][q] + bv;
      }
    }
  }
}

// ---------------- fallback: slow but correct ----------------
__global__ void gemm_naive_kernel(const float* __restrict__ x, const float* __restrict__ wgt,
                                  const float* __restrict__ bias, float* __restrict__ out,
                                  int M, int N, int K) {
  long long idx = (long long)blockIdx.x * blockDim.x + threadIdx.x;
  if (idx >= (long long)M * N) return;
  int o = (int)(idx % N);
  int m = (int)(idx / N);
  const float* xr = x + (size_t)m * K;
  const float* wr = wgt + (size_t)o * K;
  float s = 0.f;
  for (int i = 0; i < K; ++i) {
    float wv = wr[i];
    float t = (wv > 0.05f) ? 1.f : ((wv < -0.05f) ? -1.f : 0.f);
    s = fmaf(xr[i], t, s);
  }
  out[idx] = s + bias[o];
}

extern "C" void kernel_launch(void* const* d_in, const int* in_sizes, int n_in,
                              void* d_out, int out_size, void* d_ws, size_t ws_size,
                              hipStream_t stream) {
  const float* x    = (const float*)d_in[0];
  const float* wgt  = (const float*)d_in[1];
  const float* bias = (const float*)d_in[2];
  float* out = (float*)d_out;

  const int N = in_sizes[2];                 // out features
  const int K = in_sizes[1] / N;             // in features
  const int M = in_sizes[0] / K;             // batch rows

  const size_t need = ((size_t)M * K + (size_t)N * K) * sizeof(u16);
  if (ws_size >= need && (M % 256 == 0) && (N % 256 == 0) && (K % 64 == 0) && K >= 192) {
    u16* xb = (u16*)d_ws;
    u16* wb = xb + (size_t)M * K;
    const int Kt = K / 64;
    cvt_x_perm<<<(M / 256) * Kt, 256, 0, stream>>>(x, xb, K);
    quant_w_perm<<<(N / 256) * Kt, 256, 0, stream>>>(wgt, wb, K);
    const int grid = (M / 256) * (N / 256);
    gemm_bin_m201d<<<grid, 512, 0, stream>>>(xb, wb, bias, out, M, N, K);
  } else {
    const long long total = (long long)M * N;
    gemm_naive_kernel<<<(unsigned)((total + 255) / 256), 256, 0, stream>>>(x, wgt, bias, out, M, N, K);
  }
}